// Round 2
// baseline (694.714 us; speedup 1.0000x reference)
//
#include <hip/hip_runtime.h>

#define NN     256
#define NF     127
#define DIM    128
#define NH     8
#define DH     64
#define INNER  512
#define DEPTH  6
#define NB     512
#define ATTN_SCALE 0.125f
#define LN_EPS 1e-5f

__device__ __forceinline__ float wred_sum(float v){
#pragma unroll
  for(int o=32;o;o>>=1) v += __shfl_xor(v,o);
  return v;
}
__device__ __forceinline__ float wred_max(float v){
#pragma unroll
  for(int o=32;o;o>>=1) v = fmaxf(v,__shfl_xor(v,o));
  return v;
}
// block = 256 threads (4 waves). sred must have >= 16 floats.
__device__ __forceinline__ float block_sum(float v, float* sred, int t){
  v = wred_sum(v);
  __syncthreads();
  if((t&63)==0) sred[t>>6]=v;
  __syncthreads();
  return sred[0]+sred[1]+sred[2]+sred[3];
}
__device__ __forceinline__ float block_max(float v, float* sred, int t){
  v = wred_max(v);
  __syncthreads();
  if((t&63)==0) sred[t>>6]=v;
  __syncthreads();
  return fmaxf(fmaxf(sred[0],sred[1]),fmaxf(sred[2],sred[3]));
}

// LayerNorm over DIM values: in (LDS) -> out (LDS). All 256 threads call.
__device__ __forceinline__ void dev_ln(const float* in, float* out,
                                       const float* g, const float* b,
                                       float* sred, int t){
  float v = (t<DIM)? in[t] : 0.f;
  float m = block_sum(v,sred,t) * (1.f/DIM);
  float d = (t<DIM)? (v-m) : 0.f;
  float var = block_sum(d*d,sred,t) * (1.f/DIM);
  float rs = rsqrtf(var + LN_EPS);
  if(t<DIM) out[t] = d*rs*g[t] + b[t];
  __syncthreads();
}

// Q/K/V for one row i from xs[DIM] (LDS). q row-major, k transposed [o][j],
// v row-major. be folded into k and v (the bias part of the edge tensor e).
__device__ __forceinline__ void dev_qkv(const float* xs, int i,
    const float* Wq, const float* bq, const float* Wkv, const float* bkv,
    const float* be, float* qg, float* kT, float* vg, int t){
  const int o0 = 2*t;
  {
    float a0=0.f, a1=0.f;
    for(int f=0; f<DIM; f++){
      float2 w = *(const float2*)(Wq + f*INNER + o0);
      a0 = fmaf(xs[f], w.x, a0);
      a1 = fmaf(xs[f], w.y, a1);
    }
    qg[i*INNER+o0]   = a0 + bq[o0];
    qg[i*INNER+o0+1] = a1 + bq[o0+1];
  }
  {
    float a0=0.f, a1=0.f;
    for(int f=0; f<DIM; f++){
      float2 w = *(const float2*)(Wkv + f*(2*INNER) + o0);
      a0 = fmaf(xs[f], w.x, a0);
      a1 = fmaf(xs[f], w.y, a1);
    }
    kT[o0*NN+i]     = a0 + bkv[o0]   + be[o0];
    kT[(o0+1)*NN+i] = a1 + bkv[o0+1] + be[o0+1];
  }
  {
    const int o1 = INNER + o0;
    float a0=0.f, a1=0.f;
    for(int f=0; f<DIM; f++){
      float2 w = *(const float2*)(Wkv + f*(2*INNER) + o1);
      a0 = fmaf(xs[f], w.x, a0);
      a1 = fmaf(xs[f], w.y, a1);
    }
    vg[i*INNER+o0]   = a0 + bkv[o1]   + be[o0];
    vg[i*INNER+o0+1] = a1 + bkv[o1+1] + be[o0+1];
  }
}

// ---- fused node-init + LN1 + QKV for layer 0 ----
__global__ __launch_bounds__(256) void k_qkv0(const float* atom_emb, const float* noise,
    float* nodes,
    const float* ln1_g, const float* ln1_b,
    const float* Wq, const float* bq, const float* Wkv, const float* bkv, const float* be,
    float* qg, float* kT, float* vg){
  __shared__ float nd[DIM], xs[DIM], sred[16];
  int t = threadIdx.x, i = blockIdx.x;
  if(t<DIM){
    float v = (t<NF)? atom_emb[i*NF+t] : noise[0];
    nd[t] = v;
    nodes[i*DIM+t] = v;
  }
  __syncthreads();
  dev_ln(nd, xs, ln1_g, ln1_b, sred, t);
  dev_qkv(xs, i, Wq, bq, Wkv, bkv, be, qg, kT, vg, t);
}

// ---- fused per-row layer: attn(8 heads) + Wo + gate1 + FFN + gate2 (+ next QKV) ----
__global__ __launch_bounds__(256) void k_layer(
    float* nodes, const float* qg, const float* kT, const float* vg,
    float* qg_n, float* kT_n, float* vg_n,
    const int* bonds, const float* coords,
    const float* We,
    const float* Wo, const float* bo, const float* Wg1,
    const float* ln2_g, const float* ln2_b,
    const float* W1, const float* b1, const float* W2, const float* b2,
    const float* Wg2,
    const float* ln1_g_n, const float* ln1_b_n,
    const float* Wq_n, const float* bq_n, const float* Wkv_n, const float* bkv_n,
    const float* be_n, int has_next)
{
  __shared__ float nd[DIM], xs[DIM], qs[INNER], ao[INNER], o128[DIM];
  __shared__ float eL[NN*3], attnS[NN], sred[16], qWe[NH*3];
  const int t = threadIdx.x, i = blockIdx.x;

  if(t<DIM) nd[t] = nodes[i*DIM+t];
  qs[t] = qg[i*INNER+t]; qs[t+256] = qg[i*INNER+t+256];
  eL[t] = 0.f; eL[t+256] = 0.f; eL[t+512] = 0.f;
  __syncthreads();

  // build edge row i from bond list (duplicate writes carry identical values)
  for(int b=t; b<NB; b+=256){
    int bi = bonds[2*b], bj = bonds[2*b+1];
    if(bi==i || bj==i){
      float dx = coords[3*bi+0] - coords[3*bj+0];
      float dy = coords[3*bi+1] - coords[3*bj+1];
      float dz = coords[3*bi+2] - coords[3*bj+2];
      if(bi==i){ eL[bj*3+0]=dx;  eL[bj*3+1]=dy;  eL[bj*3+2]=dz;  }
      if(bj==i){ eL[bi*3+0]=-dx; eL[bi*3+1]=-dy; eL[bi*3+2]=-dz; }
    }
  }
  __syncthreads();

  if(t < NH*3){               // qWe[h][c] = q_i[h-slice] . We[c, h-slice]
    int h = t/3, c = t%3;
    float acc = 0.f;
    for(int d=0; d<DH; d++) acc = fmaf(qs[h*DH+d], We[c*INNER + h*DH + d], acc);
    qWe[t] = acc;
  }
  __syncthreads();

  for(int h=0; h<NH; h++){
    // sim for j = t
    float acc = 0.f;
    const float* kc = kT + (h*DH)*NN + t;
#pragma unroll 8
    for(int d=0; d<DH; d++) acc = fmaf(qs[h*DH+d], kc[d*NN], acc);
    acc += qWe[h*3+0]*eL[t*3+0] + qWe[h*3+1]*eL[t*3+1] + qWe[h*3+2]*eL[t*3+2];
    float sim = acc * ATTN_SCALE;
    float mx = block_max(sim, sred, t);
    float p  = expf(sim - mx);
    float s  = block_sum(p, sred, t);
    float a  = p / s;
    attnS[t] = a;
    // sc_c = sum_j a_j * edges[i,j,c]
    float c0 = a*eL[t*3+0], c1 = a*eL[t*3+1], c2 = a*eL[t*3+2];
    c0 = wred_sum(c0); c1 = wred_sum(c1); c2 = wred_sum(c2);
    __syncthreads();                    // also publishes attnS
    if((t&63)==0){ int w=t>>6; sred[w*3]=c0; sred[w*3+1]=c1; sred[w*3+2]=c2; }
    __syncthreads();
    float sc0 = sred[0]+sred[3]+sred[6]+sred[9];
    float sc1 = sred[1]+sred[4]+sred[7]+sred[10];
    float sc2 = sred[2]+sred[5]+sred[8]+sred[11];
    // out: wave w sums its 64 j's for lane d
    int w = t>>6, d = t&63;
    float po = 0.f;
    const float* vcol = vg + h*DH + d;
#pragma unroll 4
    for(int jj=0; jj<64; jj++){
      int j = w*64 + jj;
      po = fmaf(attnS[j], vcol[j*INNER], po);
    }
    __syncthreads();
    attnS[t] = po;
    __syncthreads();
    if(t<DH){
      float out = attnS[t] + attnS[64+t] + attnS[128+t] + attnS[192+t];
      out += sc0*We[0*INNER+h*DH+t] + sc1*We[1*INNER+h*DH+t]
           + sc2*We[2*INNER+h*DH+t];
      ao[h*DH+t] = out;
    }
    __syncthreads();
  }

  // ---- Wo + gate1 ----
  {
    int f0 = (t&63)*2, qd = t>>6;
    float a0=0.f, a1=0.f;
    for(int r=qd*128; r<qd*128+128; r++){
      float2 w = *(const float2*)(Wo + r*DIM + f0);
      a0 = fmaf(ao[r], w.x, a0);
      a1 = fmaf(ao[r], w.y, a1);
    }
    qs[qd*DIM + f0]   = a0;          // qs free: q row no longer needed
    qs[qd*DIM + f0+1] = a1;
    __syncthreads();
    if(t<DIM) o128[t] = qs[t] + qs[DIM+t] + qs[2*DIM+t] + qs[3*DIM+t] + bo[t];
    __syncthreads();
    float gv = 0.f;
    if(t<DIM){
      float o = o128[t], r = nd[t];
      gv = o*Wg1[t] + r*Wg1[DIM+t] + (o-r)*Wg1[2*DIM+t];
    }
    float gs = block_sum(gv, sred, t);
    float gate = 1.f/(1.f + expf(-gs));
    if(t<DIM) nd[t] = o128[t]*gate + nd[t]*(1.f-gate);
    __syncthreads();
  }

  // ---- LN2 + FFN(gelu exact) + gate2 ----
  dev_ln(nd, xs, ln2_g, ln2_b, sred, t);
  {
    const int m0 = 2*t;
    float a0=0.f, a1=0.f;
    for(int f=0; f<DIM; f++){
      float2 w = *(const float2*)(W1 + f*INNER + m0);
      a0 = fmaf(xs[f], w.x, a0);
      a1 = fmaf(xs[f], w.y, a1);
    }
    a0 += b1[m0]; a1 += b1[m0+1];
    qs[m0]   = 0.5f*a0*(1.f + erff(a0*0.70710678118654752440f));
    qs[m0+1] = 0.5f*a1*(1.f + erff(a1*0.70710678118654752440f));
  }
  __syncthreads();
  {
    int f0 = (t&63)*2, qd = t>>6;
    float a0=0.f, a1=0.f;
    for(int m=qd*128; m<qd*128+128; m++){
      float2 w = *(const float2*)(W2 + m*DIM + f0);
      a0 = fmaf(qs[m], w.x, a0);
      a1 = fmaf(qs[m], w.y, a1);
    }
    ao[qd*DIM + f0]   = a0;          // ao free after Wo
    ao[qd*DIM + f0+1] = a1;
    __syncthreads();
    if(t<DIM) o128[t] = ao[t] + ao[DIM+t] + ao[2*DIM+t] + ao[3*DIM+t] + b2[t];
    __syncthreads();
    float gv = 0.f;
    if(t<DIM){
      float y = o128[t], r = nd[t];
      gv = y*Wg2[t] + r*Wg2[DIM+t] + (y-r)*Wg2[2*DIM+t];
    }
    float gs = block_sum(gv, sred, t);
    float gate = 1.f/(1.f + expf(-gs));
    if(t<DIM) nd[t] = o128[t]*gate + nd[t]*(1.f-gate);
    __syncthreads();
  }
  if(t<DIM) nodes[i*DIM+t] = nd[t];

  // ---- next layer's LN1+QKV (writes the OTHER q/k/v buffer: no race) ----
  if(has_next){
    dev_ln(nd, xs, ln1_g_n, ln1_b_n, sred, t);
    dev_qkv(xs, i, Wq_n, bq_n, Wkv_n, bkv_n, be_n, qg_n, kT_n, vg_n, t);
  }
}

__global__ __launch_bounds__(256) void k_energy(const float* nodes, const float* out_w,
                                                const float* out_b, float* out){
  int i = threadIdx.x;
  float acc = out_b[0];
  for(int f=0; f<DIM; f++) acc = fmaf(nodes[i*DIM+f], out_w[f], acc);
  out[i] = acc;
}

extern "C" void kernel_launch(void* const* d_in, const int* in_sizes, int n_in,
                              void* d_out, int out_size, void* d_ws, size_t ws_size,
                              hipStream_t stream){
  const float* coords   = (const float*)d_in[0];
  const int*   bonds    = (const int*  )d_in[1];
  const float* noise    = (const float*)d_in[2];
  const float* atom_emb = (const float*)d_in[3];
  const float* ln1_g = (const float*)d_in[4];
  const float* ln1_b = (const float*)d_in[5];
  const float* Wq    = (const float*)d_in[6];
  const float* bq    = (const float*)d_in[7];
  const float* Wkv   = (const float*)d_in[8];
  const float* bkv   = (const float*)d_in[9];
  const float* We    = (const float*)d_in[10];
  const float* be    = (const float*)d_in[11];
  const float* Wo    = (const float*)d_in[12];
  const float* bo    = (const float*)d_in[13];
  const float* Wg1   = (const float*)d_in[14];
  const float* ln2_g = (const float*)d_in[15];
  const float* ln2_b = (const float*)d_in[16];
  const float* W1    = (const float*)d_in[17];
  const float* b1    = (const float*)d_in[18];
  const float* W2    = (const float*)d_in[19];
  const float* b2    = (const float*)d_in[20];
  const float* Wg2   = (const float*)d_in[21];
  const float* out_w = (const float*)d_in[22];
  const float* out_b = (const float*)d_in[23];

  // workspace (fp32): ~3.3 MB total
  float* ws = (float*)d_ws;
  float* nodes   = ws;                              // 32768 floats
  float* qbuf[2] = { ws +  32768, ws + 163840 };    // 131072 each
  float* kbuf[2] = { ws + 294912, ws + 425984 };    // transposed [o][j]
  float* vbuf[2] = { ws + 557056, ws + 688128 };    // row-major [j][o]

  k_qkv0<<<256, 256, 0, stream>>>(atom_emb, noise, nodes, ln1_g, ln1_b,
                                  Wq, bq, Wkv, bkv, be,
                                  qbuf[0], kbuf[0], vbuf[0]);
  for(int l=0; l<DEPTH; l++){
    int cur = l&1, nxt = cur^1;
    int has_next = (l < DEPTH-1);
    int ln = has_next ? l+1 : l;    // keep pointers valid when unused
    k_layer<<<256, 256, 0, stream>>>(
      nodes, qbuf[cur], kbuf[cur], vbuf[cur],
      qbuf[nxt], kbuf[nxt], vbuf[nxt],
      bonds, coords,
      We  + (size_t)l*3*INNER,
      Wo  + (size_t)l*INNER*DIM, bo + (size_t)l*DIM, Wg1 + (size_t)l*3*DIM,
      ln2_g + (size_t)l*DIM, ln2_b + (size_t)l*DIM,
      W1  + (size_t)l*DIM*4*DIM, b1 + (size_t)l*4*DIM,
      W2  + (size_t)l*4*DIM*DIM, b2 + (size_t)l*DIM, Wg2 + (size_t)l*3*DIM,
      ln1_g + (size_t)ln*DIM, ln1_b + (size_t)ln*DIM,
      Wq  + (size_t)ln*DIM*INNER, bq + (size_t)ln*INNER,
      Wkv + (size_t)ln*DIM*2*INNER, bkv + (size_t)ln*2*INNER,
      be  + (size_t)ln*INNER, has_next);
  }
  k_energy<<<1, 256, 0, stream>>>(nodes, out_w, out_b, (float*)d_out);
}

// Round 3
// 433.715 us; speedup vs baseline: 1.6018x; 1.6018x over previous
//
#include <hip/hip_runtime.h>

#define NN     256
#define NF     127
#define DIM    128
#define NH     8
#define DH     64
#define INNER  512
#define DEPTH  6
#define NB     512
#define ATTN_SCALE 0.125f
#define LN_EPS 1e-5f

__device__ __forceinline__ float wred_sum(float v){
#pragma unroll
  for(int o=32;o;o>>=1) v += __shfl_xor(v,o);
  return v;
}
__device__ __forceinline__ float wred_max(float v){
#pragma unroll
  for(int o=32;o;o>>=1) v = fmaxf(v,__shfl_xor(v,o));
  return v;
}
// block = 512 threads (8 waves). sred must have >= 8 floats.
__device__ __forceinline__ float block_sum(float v, float* sred, int t){
  v = wred_sum(v);
  __syncthreads();
  if((t&63)==0) sred[t>>6]=v;
  __syncthreads();
  float s = 0.f;
#pragma unroll
  for(int w=0; w<8; w++) s += sred[w];
  return s;
}

// LayerNorm over DIM values: in (LDS) -> out (LDS). All 512 threads call.
__device__ __forceinline__ void dev_ln(const float* in, float* out,
                                       const float* g, const float* b,
                                       float* sred, int t){
  float v = (t<DIM)? in[t] : 0.f;
  float m = block_sum(v,sred,t) * (1.f/DIM);
  float d = (t<DIM)? (v-m) : 0.f;
  float var = block_sum(d*d,sred,t) * (1.f/DIM);
  float rs = rsqrtf(var + LN_EPS);
  if(t<DIM) out[t] = d*rs*g[t] + b[t];
  __syncthreads();
}

// Q/K/V for one row i from xs[DIM] (LDS). 512 threads: one column each.
// q row-major, k transposed [o][j], v row-major. be folded into k and v.
__device__ __forceinline__ void dev_qkv(const float* xs, int i,
    const float* Wq, const float* bq, const float* Wkv, const float* bkv,
    const float* be, float* qg, float* kT, float* vg, int t){
  {
    float a0=0.f, a1=0.f;
#pragma unroll 4
    for(int f=0; f<DIM; f+=2){
      a0 = fmaf(xs[f],   Wq[f*INNER+t],     a0);
      a1 = fmaf(xs[f+1], Wq[(f+1)*INNER+t], a1);
    }
    qg[i*INNER+t] = a0+a1 + bq[t];
  }
  {
    float a0=0.f, a1=0.f;
#pragma unroll 4
    for(int f=0; f<DIM; f+=2){
      a0 = fmaf(xs[f],   Wkv[f*(2*INNER)+t],     a0);
      a1 = fmaf(xs[f+1], Wkv[(f+1)*(2*INNER)+t], a1);
    }
    kT[t*NN+i] = a0+a1 + bkv[t] + be[t];
  }
  {
    float a0=0.f, a1=0.f;
#pragma unroll 4
    for(int f=0; f<DIM; f+=2){
      a0 = fmaf(xs[f],   Wkv[f*(2*INNER)+INNER+t],     a0);
      a1 = fmaf(xs[f+1], Wkv[(f+1)*(2*INNER)+INNER+t], a1);
    }
    vg[i*INNER+t] = a0+a1 + bkv[INNER+t] + be[t];
  }
}

// ---- fused node-init + LN1 + QKV for layer 0 ----
__global__ __launch_bounds__(512) void k_qkv0(const float* atom_emb, const float* noise,
    float* nodes,
    const float* ln1_g, const float* ln1_b,
    const float* Wq, const float* bq, const float* Wkv, const float* bkv, const float* be,
    float* qg, float* kT, float* vg){
  __shared__ float nd[DIM], xs[DIM], sred[8];
  int t = threadIdx.x, i = blockIdx.x;
  if(t<DIM){
    float v = (t<NF)? atom_emb[i*NF+t] : noise[0];
    nd[t] = v;
    nodes[i*DIM+t] = v;
  }
  __syncthreads();
  dev_ln(nd, xs, ln1_g, ln1_b, sred, t);
  dev_qkv(xs, i, Wq, bq, Wkv, bkv, be, qg, kT, vg, t);
}

// ---- fused per-row layer (512 thr): wave-per-head attn + Wo + gate1 + FFN + gate2 (+ next QKV)
__global__ __launch_bounds__(512) void k_layer(
    float* nodes, const float* qg, const float* kT, const float* vg,
    float* qg_n, float* kT_n, float* vg_n,
    const int* bonds, const float* coords,
    const float* We,
    const float* Wo, const float* bo, const float* Wg1,
    const float* ln2_g, const float* ln2_b,
    const float* W1, const float* b1, const float* W2, const float* b2,
    const float* Wg2,
    const float* ln1_g_n, const float* ln1_b_n,
    const float* Wq_n, const float* bq_n, const float* Wkv_n, const float* bkv_n,
    const float* be_n, int has_next)
{
  __shared__ float nd[DIM], xs[DIM], qs[INNER], ao[INNER], o128[DIM];
  __shared__ float eL[NN*3], aW[NH*NN], red8[8*DIM], sred[8], qWe[NH*3];
  const int t = threadIdx.x, i = blockIdx.x;

  if(t<DIM) nd[t] = nodes[i*DIM+t];
  qs[t] = qg[i*INNER+t];
  eL[t] = 0.f;
  if(t<NN) eL[512+t] = 0.f;
  __syncthreads();

  // build edge row i from bond list (duplicate writes carry identical values)
  {
    int bi = bonds[2*t], bj = bonds[2*t+1];
    if(bi==i || bj==i){
      float dx = coords[3*bi+0] - coords[3*bj+0];
      float dy = coords[3*bi+1] - coords[3*bj+1];
      float dz = coords[3*bi+2] - coords[3*bj+2];
      if(bi==i){ eL[bj*3+0]=dx;  eL[bj*3+1]=dy;  eL[bj*3+2]=dz;  }
      if(bj==i){ eL[bi*3+0]=-dx; eL[bi*3+1]=-dy; eL[bi*3+2]=-dz; }
    }
  }
  __syncthreads();

  if(t < NH*3){               // qWe[h][c] = q_i[h-slice] . We[c, h-slice]
    int h = t/3, c = t%3;
    float acc = 0.f;
    for(int d=0; d<DH; d++) acc = fmaf(qs[h*DH+d], We[c*INNER + h*DH + d], acc);
    qWe[t] = acc;
  }
  __syncthreads();

  // ---- attention: wave w == head w, lane l owns j in {4l..4l+3}. no block barriers ----
  {
    const int h = t>>6, l = t&63, j0 = 4*l;
    const float* kTh = kT + (h*DH)*NN;
    float s0=0.f,s1=0.f,s2=0.f,s3=0.f;
#pragma unroll 4
    for(int o=0; o<DH; o++){
      float qv = qs[h*DH+o];
      float4 kk = *(const float4*)(kTh + o*NN + j0);
      s0=fmaf(qv,kk.x,s0); s1=fmaf(qv,kk.y,s1); s2=fmaf(qv,kk.z,s2); s3=fmaf(qv,kk.w,s3);
    }
    float w0=qWe[h*3+0], w1=qWe[h*3+1], w2=qWe[h*3+2];
    s0 += w0*eL[(j0+0)*3+0] + w1*eL[(j0+0)*3+1] + w2*eL[(j0+0)*3+2];
    s1 += w0*eL[(j0+1)*3+0] + w1*eL[(j0+1)*3+1] + w2*eL[(j0+1)*3+2];
    s2 += w0*eL[(j0+2)*3+0] + w1*eL[(j0+2)*3+1] + w2*eL[(j0+2)*3+2];
    s3 += w0*eL[(j0+3)*3+0] + w1*eL[(j0+3)*3+1] + w2*eL[(j0+3)*3+2];
    s0*=ATTN_SCALE; s1*=ATTN_SCALE; s2*=ATTN_SCALE; s3*=ATTN_SCALE;
    float mx = wred_max(fmaxf(fmaxf(s0,s1),fmaxf(s2,s3)));
    float p0=expf(s0-mx), p1=expf(s1-mx), p2=expf(s2-mx), p3=expf(s3-mx);
    float inv = 1.f / wred_sum(p0+p1+p2+p3);
    float a0=p0*inv, a1=p1*inv, a2=p2*inv, a3=p3*inv;
    float* aw = aW + h*NN;
    *(float4*)(aw + j0) = make_float4(a0,a1,a2,a3);
    // sc_c = sum_j a_j * edges[i,j,c]
    float c0 = a0*eL[(j0+0)*3+0]+a1*eL[(j0+1)*3+0]+a2*eL[(j0+2)*3+0]+a3*eL[(j0+3)*3+0];
    float c1 = a0*eL[(j0+0)*3+1]+a1*eL[(j0+1)*3+1]+a2*eL[(j0+2)*3+1]+a3*eL[(j0+3)*3+1];
    float c2 = a0*eL[(j0+0)*3+2]+a1*eL[(j0+1)*3+2]+a2*eL[(j0+2)*3+2]+a3*eL[(j0+3)*3+2];
    c0 = wred_sum(c0); c1 = wred_sum(c1); c2 = wred_sum(c2);
    __builtin_amdgcn_wave_barrier();   // keep aW write before aW reads (no-op at runtime)
    // out[d]: lane d accumulates over all j
    const int d = l;
    const float* vcol = vg + h*DH + d;
    float x0=0.f,x1=0.f,x2=0.f,x3=0.f;
#pragma unroll 4
    for(int j=0; j<NN; j+=4){
      x0 = fmaf(aw[j+0], vcol[(j+0)*INNER], x0);
      x1 = fmaf(aw[j+1], vcol[(j+1)*INNER], x1);
      x2 = fmaf(aw[j+2], vcol[(j+2)*INNER], x2);
      x3 = fmaf(aw[j+3], vcol[(j+3)*INNER], x3);
    }
    float out = (x0+x1)+(x2+x3);
    out += c0*We[0*INNER+h*DH+d] + c1*We[1*INNER+h*DH+d] + c2*We[2*INNER+h*DH+d];
    ao[h*DH+d] = out;
  }
  __syncthreads();

  // ---- Wo + gate1 ---- (8 row-octants of 64, 2 cols/thread)
  {
    int c2 = (t&63)*2, oct = t>>6;
    float a0=0.f, a1=0.f;
#pragma unroll 4
    for(int r=oct*64; r<oct*64+64; r++){
      float2 w = *(const float2*)(Wo + r*DIM + c2);
      a0 = fmaf(ao[r], w.x, a0);
      a1 = fmaf(ao[r], w.y, a1);
    }
    red8[oct*DIM + c2]   = a0;
    red8[oct*DIM + c2+1] = a1;
    __syncthreads();
    if(t<DIM){
      float s = bo[t];
#pragma unroll
      for(int o=0;o<8;o++) s += red8[o*DIM+t];
      o128[t] = s;
    }
    __syncthreads();
    float gv = 0.f;
    if(t<DIM){
      float o = o128[t], r = nd[t];
      gv = o*Wg1[t] + r*Wg1[DIM+t] + (o-r)*Wg1[2*DIM+t];
    }
    float gs = block_sum(gv, sred, t);
    float gate = 1.f/(1.f + expf(-gs));
    if(t<DIM) nd[t] = o128[t]*gate + nd[t]*(1.f-gate);
    __syncthreads();
  }

  // ---- LN2 + FFN(gelu exact) + gate2 ----
  dev_ln(nd, xs, ln2_g, ln2_b, sred, t);
  {
    float a0=0.f, a1=0.f;
#pragma unroll 4
    for(int f=0; f<DIM; f+=2){
      a0 = fmaf(xs[f],   W1[f*INNER+t],     a0);
      a1 = fmaf(xs[f+1], W1[(f+1)*INNER+t], a1);
    }
    float a = a0+a1 + b1[t];
    qs[t] = 0.5f*a*(1.f + erff(a*0.70710678118654752440f));
  }
  __syncthreads();
  {
    int c2 = (t&63)*2, oct = t>>6;
    float a0=0.f, a1=0.f;
#pragma unroll 4
    for(int m=oct*64; m<oct*64+64; m++){
      float2 w = *(const float2*)(W2 + m*DIM + c2);
      a0 = fmaf(qs[m], w.x, a0);
      a1 = fmaf(qs[m], w.y, a1);
    }
    red8[oct*DIM + c2]   = a0;
    red8[oct*DIM + c2+1] = a1;
    __syncthreads();
    if(t<DIM){
      float s = b2[t];
#pragma unroll
      for(int o=0;o<8;o++) s += red8[o*DIM+t];
      o128[t] = s;
    }
    __syncthreads();
    float gv = 0.f;
    if(t<DIM){
      float y = o128[t], r = nd[t];
      gv = y*Wg2[t] + r*Wg2[DIM+t] + (y-r)*Wg2[2*DIM+t];
    }
    float gs = block_sum(gv, sred, t);
    float gate = 1.f/(1.f + expf(-gs));
    if(t<DIM) nd[t] = o128[t]*gate + nd[t]*(1.f-gate);
    __syncthreads();
  }
  if(t<DIM) nodes[i*DIM+t] = nd[t];

  // ---- next layer's LN1+QKV (writes the OTHER q/k/v buffer: no race) ----
  if(has_next){
    dev_ln(nd, xs, ln1_g_n, ln1_b_n, sred, t);
    dev_qkv(xs, i, Wq_n, bq_n, Wkv_n, bkv_n, be_n, qg_n, kT_n, vg_n, t);
  }
}

__global__ __launch_bounds__(64) void k_energy(const float* nodes, const float* out_w,
                                               const float* out_b, float* out){
  int i = blockIdx.x, l = threadIdx.x;
  float a = fmaf(nodes[i*DIM+l], out_w[l], nodes[i*DIM+64+l]*out_w[64+l]);
  a = wred_sum(a);
  if(l==0) out[i] = a + out_b[0];
}

extern "C" void kernel_launch(void* const* d_in, const int* in_sizes, int n_in,
                              void* d_out, int out_size, void* d_ws, size_t ws_size,
                              hipStream_t stream){
  const float* coords   = (const float*)d_in[0];
  const int*   bonds    = (const int*  )d_in[1];
  const float* noise    = (const float*)d_in[2];
  const float* atom_emb = (const float*)d_in[3];
  const float* ln1_g = (const float*)d_in[4];
  const float* ln1_b = (const float*)d_in[5];
  const float* Wq    = (const float*)d_in[6];
  const float* bq    = (const float*)d_in[7];
  const float* Wkv   = (const float*)d_in[8];
  const float* bkv   = (const float*)d_in[9];
  const float* We    = (const float*)d_in[10];
  const float* be    = (const float*)d_in[11];
  const float* Wo    = (const float*)d_in[12];
  const float* bo    = (const float*)d_in[13];
  const float* Wg1   = (const float*)d_in[14];
  const float* ln2_g = (const float*)d_in[15];
  const float* ln2_b = (const float*)d_in[16];
  const float* W1    = (const float*)d_in[17];
  const float* b1    = (const float*)d_in[18];
  const float* W2    = (const float*)d_in[19];
  const float* b2    = (const float*)d_in[20];
  const float* Wg2   = (const float*)d_in[21];
  const float* out_w = (const float*)d_in[22];
  const float* out_b = (const float*)d_in[23];

  // workspace (fp32): ~3.3 MB total
  float* ws = (float*)d_ws;
  float* nodes   = ws;                              // 32768 floats
  float* qbuf[2] = { ws +  32768, ws + 163840 };    // 131072 each
  float* kbuf[2] = { ws + 294912, ws + 425984 };    // transposed [o][j]
  float* vbuf[2] = { ws + 557056, ws + 688128 };    // row-major [j][o]

  k_qkv0<<<256, 512, 0, stream>>>(atom_emb, noise, nodes, ln1_g, ln1_b,
                                  Wq, bq, Wkv, bkv, be,
                                  qbuf[0], kbuf[0], vbuf[0]);
  for(int l=0; l<DEPTH; l++){
    int cur = l&1, nxt = cur^1;
    int has_next = (l < DEPTH-1);
    int ln = has_next ? l+1 : l;    // keep pointers valid when unused
    k_layer<<<256, 512, 0, stream>>>(
      nodes, qbuf[cur], kbuf[cur], vbuf[cur],
      qbuf[nxt], kbuf[nxt], vbuf[nxt],
      bonds, coords,
      We  + (size_t)l*3*INNER,
      Wo  + (size_t)l*INNER*DIM, bo + (size_t)l*DIM, Wg1 + (size_t)l*3*DIM,
      ln2_g + (size_t)l*DIM, ln2_b + (size_t)l*DIM,
      W1  + (size_t)l*DIM*4*DIM, b1 + (size_t)l*4*DIM,
      W2  + (size_t)l*4*DIM*DIM, b2 + (size_t)l*DIM, Wg2 + (size_t)l*3*DIM,
      ln1_g + (size_t)ln*DIM, ln1_b + (size_t)ln*DIM,
      Wq  + (size_t)ln*DIM*INNER, bq + (size_t)ln*INNER,
      Wkv + (size_t)ln*DIM*2*INNER, bkv + (size_t)ln*2*INNER,
      be  + (size_t)ln*INNER, has_next);
  }
  k_energy<<<256, 64, 0, stream>>>(nodes, out_w, out_b, (float*)d_out);
}

// Round 4
// 320.100 us; speedup vs baseline: 2.1703x; 1.3549x over previous
//
#include <hip/hip_runtime.h>

#define NN     256
#define NF     127
#define DIM    128
#define NH     8
#define DH     64
#define INNER  512
#define DEPTH  6
#define NB     512
#define ATTN_SCALE 0.125f
#define LN_EPS 1e-5f

__device__ __forceinline__ float wred_sum(float v){
#pragma unroll
  for(int o=32;o;o>>=1) v += __shfl_xor(v,o);
  return v;
}
__device__ __forceinline__ float wred_max(float v){
#pragma unroll
  for(int o=32;o;o>>=1) v = fmaxf(v,__shfl_xor(v,o));
  return v;
}
// block = 512 threads (8 waves). sred must have >= 8 floats.
__device__ __forceinline__ float block_sum(float v, float* sred, int t){
  v = wred_sum(v);
  __syncthreads();
  if((t&63)==0) sred[t>>6]=v;
  __syncthreads();
  float s = 0.f;
#pragma unroll
  for(int w=0; w<8; w++) s += sred[w];
  return s;
}

// LayerNorm over DIM values: in (LDS) -> out (LDS). All 512 threads call.
__device__ __forceinline__ void dev_ln(const float* in, float* out,
                                       const float* g, const float* b,
                                       float* sred, int t){
  float v = (t<DIM)? in[t] : 0.f;
  float m = block_sum(v,sred,t) * (1.f/DIM);
  float d = (t<DIM)? (v-m) : 0.f;
  float var = block_sum(d*d,sred,t) * (1.f/DIM);
  float rs = rsqrtf(var + LN_EPS);
  if(t<DIM) out[t] = d*rs*g[t] + b[t];
  __syncthreads();
}

// Q/K/V for one row i from xs[DIM] (LDS), float4 weight loads + LDS reduction.
// q row-major, k transposed [o][j], v row-major. be folded into k and v.
// redS: 2048-float LDS scratch. Ends with redS free (after final barrier).
__device__ __forceinline__ void dev_qkv4(const float* xs, int i,
    const float* Wq, const float* bq, const float* Wkv, const float* bkv,
    const float* be, float* qg, float* kT, float* vg, float* redS, int t){
  // ---- q: 128 col-groups(4) x 4 row-quarters(32) ----
  {
    const int cg4 = (t&127)*4, rq = t>>7;
    float4 acc = make_float4(0.f,0.f,0.f,0.f);
#pragma unroll
    for(int f=rq*32; f<rq*32+32; f++){
      float x = xs[f];
      float4 w = *(const float4*)(Wq + f*INNER + cg4);
      acc.x=fmaf(x,w.x,acc.x); acc.y=fmaf(x,w.y,acc.y);
      acc.z=fmaf(x,w.z,acc.z); acc.w=fmaf(x,w.w,acc.w);
    }
    *(float4*)(redS + rq*INNER + cg4) = acc;
  }
  __syncthreads();
  qg[i*INNER+t] = bq[t] + redS[t] + redS[INNER+t] + redS[2*INNER+t] + redS[3*INNER+t];
  __syncthreads();
  // ---- kv: 256 col-groups(4) x 2 row-halves(64) ----
  {
    const int cg4 = (t&255)*4, rh = t>>8;
    float4 acc = make_float4(0.f,0.f,0.f,0.f);
#pragma unroll 8
    for(int f=rh*64; f<rh*64+64; f++){
      float x = xs[f];
      float4 w = *(const float4*)(Wkv + f*(2*INNER) + cg4);
      acc.x=fmaf(x,w.x,acc.x); acc.y=fmaf(x,w.y,acc.y);
      acc.z=fmaf(x,w.z,acc.z); acc.w=fmaf(x,w.w,acc.w);
    }
    *(float4*)(redS + rh*(2*INNER) + cg4) = acc;
  }
  __syncthreads();
#pragma unroll
  for(int cc=0; cc<2; cc++){
    int c = t + cc*512;
    float s = redS[c] + redS[2*INNER+c] + bkv[c];
    if(c < INNER) kT[c*NN+i]          = s + be[c];
    else          vg[i*INNER+c-INNER] = s + be[c-INNER];
  }
  __syncthreads();
}

// ---- fused node-init + LN1 + QKV for layer 0 ----
__global__ __launch_bounds__(512) void k_qkv0(const float* atom_emb, const float* noise,
    float* nodes,
    const float* ln1_g, const float* ln1_b,
    const float* Wq, const float* bq, const float* Wkv, const float* bkv, const float* be,
    float* qg, float* kT, float* vg){
  __shared__ float nd[DIM], xs[DIM], sred[8], redS[2048];
  int t = threadIdx.x, i = blockIdx.x;
  if(t<DIM){
    float v = (t<NF)? atom_emb[i*NF+t] : noise[0];
    nd[t] = v;
    nodes[i*DIM+t] = v;
  }
  __syncthreads();
  dev_ln(nd, xs, ln1_g, ln1_b, sred, t);
  dev_qkv4(xs, i, Wq, bq, Wkv, bkv, be, qg, kT, vg, redS, t);
}

// ---- fused per-row layer (512 thr): wave-per-head attn + Wo + gate1 + FFN + gate2 (+ next QKV)
__global__ __launch_bounds__(512) void k_layer(
    float* nodes, const float* qg, const float* kT, const float* vg,
    float* qg_n, float* kT_n, float* vg_n,
    const int* bonds, const float* coords,
    const float* We,
    const float* Wo, const float* bo, const float* Wg1,
    const float* ln2_g, const float* ln2_b,
    const float* W1, const float* b1, const float* W2, const float* b2,
    const float* Wg2,
    const float* ln1_g_n, const float* ln1_b_n,
    const float* Wq_n, const float* bq_n, const float* Wkv_n, const float* bkv_n,
    const float* be_n, int has_next)
{
  __shared__ float nd[DIM], xs[DIM], qs[INNER], ao[INNER], o128[DIM];
  __shared__ float eL[NN*3], aW[NH*NN], redS[2048], sred[8], qWe[NH*3];
  const int t = threadIdx.x, i = blockIdx.x;

  if(t<DIM) nd[t] = nodes[i*DIM+t];
  qs[t] = qg[i*INNER+t];
  eL[t] = 0.f;
  if(t<NN) eL[512+t] = 0.f;
  __syncthreads();

  // build edge row i from bond list (duplicate writes carry identical values)
  {
    int bi = bonds[2*t], bj = bonds[2*t+1];
    if(bi==i || bj==i){
      float dx = coords[3*bi+0] - coords[3*bj+0];
      float dy = coords[3*bi+1] - coords[3*bj+1];
      float dz = coords[3*bi+2] - coords[3*bj+2];
      if(bi==i){ eL[bj*3+0]=dx;  eL[bj*3+1]=dy;  eL[bj*3+2]=dz;  }
      if(bj==i){ eL[bi*3+0]=-dx; eL[bi*3+1]=-dy; eL[bi*3+2]=-dz; }
    }
  }
  __syncthreads();

  if(t < NH*3){               // qWe[h][c] = q_i[h-slice] . We[c, h-slice]
    int h = t/3, c = t%3;
    float acc = 0.f;
    for(int d=0; d<DH; d++) acc = fmaf(qs[h*DH+d], We[c*INNER + h*DH + d], acc);
    qWe[t] = acc;
  }
  __syncthreads();

  // ---- attention: wave w == head w. no block barriers ----
  {
    const int h = t>>6, l = t&63, j0 = 4*l;
    const float* kTh = kT + (h*DH)*NN;
    float s0=0.f,s1=0.f,s2=0.f,s3=0.f;
#pragma unroll 8
    for(int o=0; o<DH; o++){
      float qv = qs[h*DH+o];
      float4 kk = *(const float4*)(kTh + o*NN + j0);
      s0=fmaf(qv,kk.x,s0); s1=fmaf(qv,kk.y,s1); s2=fmaf(qv,kk.z,s2); s3=fmaf(qv,kk.w,s3);
    }
    float w0=qWe[h*3+0], w1=qWe[h*3+1], w2=qWe[h*3+2];
    s0 += w0*eL[(j0+0)*3+0] + w1*eL[(j0+0)*3+1] + w2*eL[(j0+0)*3+2];
    s1 += w0*eL[(j0+1)*3+0] + w1*eL[(j0+1)*3+1] + w2*eL[(j0+1)*3+2];
    s2 += w0*eL[(j0+2)*3+0] + w1*eL[(j0+2)*3+1] + w2*eL[(j0+2)*3+2];
    s3 += w0*eL[(j0+3)*3+0] + w1*eL[(j0+3)*3+1] + w2*eL[(j0+3)*3+2];
    s0*=ATTN_SCALE; s1*=ATTN_SCALE; s2*=ATTN_SCALE; s3*=ATTN_SCALE;
    float mx = wred_max(fmaxf(fmaxf(s0,s1),fmaxf(s2,s3)));
    float p0=expf(s0-mx), p1=expf(s1-mx), p2=expf(s2-mx), p3=expf(s3-mx);
    float inv = 1.f / wred_sum(p0+p1+p2+p3);
    float a0=p0*inv, a1=p1*inv, a2=p2*inv, a3=p3*inv;
    float* aw = aW + h*NN;
    *(float4*)(aw + j0) = make_float4(a0,a1,a2,a3);
    // sc_c = sum_j a_j * edges[i,j,c]
    float c0 = a0*eL[(j0+0)*3+0]+a1*eL[(j0+1)*3+0]+a2*eL[(j0+2)*3+0]+a3*eL[(j0+3)*3+0];
    float c1 = a0*eL[(j0+0)*3+1]+a1*eL[(j0+1)*3+1]+a2*eL[(j0+2)*3+1]+a3*eL[(j0+3)*3+1];
    float c2 = a0*eL[(j0+0)*3+2]+a1*eL[(j0+1)*3+2]+a2*eL[(j0+2)*3+2]+a3*eL[(j0+3)*3+2];
    c0 = wred_sum(c0); c1 = wred_sum(c1); c2 = wred_sum(c2);
    __builtin_amdgcn_wave_barrier();   // order aW write before aW reads (no-op at runtime)
    // PV: lane l -> 4 outputs dq..dq+3, j-range jg*64..+63; fold over jg via shuffles
    const int dq = (l&15)*4, jg = l>>4;
    const float* vb = vg + h*DH + dq;
    float4 acc = make_float4(0.f,0.f,0.f,0.f);
#pragma unroll 8
    for(int jj=0; jj<64; jj++){
      int j = jg*64 + jj;
      float a = aw[j];
      float4 vv = *(const float4*)(vb + j*INNER);
      acc.x=fmaf(a,vv.x,acc.x); acc.y=fmaf(a,vv.y,acc.y);
      acc.z=fmaf(a,vv.z,acc.z); acc.w=fmaf(a,vv.w,acc.w);
    }
#pragma unroll
    for(int o=16;o<64;o<<=1){
      acc.x += __shfl_xor(acc.x,o); acc.y += __shfl_xor(acc.y,o);
      acc.z += __shfl_xor(acc.z,o); acc.w += __shfl_xor(acc.w,o);
    }
    if(l<16){
      float4 we0 = *(const float4*)(We + 0*INNER + h*DH + dq);
      float4 we1 = *(const float4*)(We + 1*INNER + h*DH + dq);
      float4 we2 = *(const float4*)(We + 2*INNER + h*DH + dq);
      float4 o;
      o.x = acc.x + c0*we0.x + c1*we1.x + c2*we2.x;
      o.y = acc.y + c0*we0.y + c1*we1.y + c2*we2.y;
      o.z = acc.z + c0*we0.z + c1*we1.z + c2*we2.z;
      o.w = acc.w + c0*we0.w + c1*we1.w + c2*we2.w;
      *(float4*)(ao + h*DH + dq) = o;
    }
  }
  __syncthreads();

  // ---- Wo + gate1 ---- (32 col-groups(4) x 16 row-groups(32))
  {
    const int cg4 = (t&31)*4, rg = t>>5;
    float4 acc = make_float4(0.f,0.f,0.f,0.f);
#pragma unroll
    for(int r=rg*32; r<rg*32+32; r++){
      float a = ao[r];
      float4 w = *(const float4*)(Wo + r*DIM + cg4);
      acc.x=fmaf(a,w.x,acc.x); acc.y=fmaf(a,w.y,acc.y);
      acc.z=fmaf(a,w.z,acc.z); acc.w=fmaf(a,w.w,acc.w);
    }
    *(float4*)(redS + rg*DIM + cg4) = acc;
    __syncthreads();
    if(t<DIM){
      float s = bo[t];
#pragma unroll
      for(int g=0; g<16; g++) s += redS[g*DIM+t];
      o128[t] = s;
    }
    __syncthreads();
    float gv = 0.f;
    if(t<DIM){
      float o = o128[t], r = nd[t];
      gv = o*Wg1[t] + r*Wg1[DIM+t] + (o-r)*Wg1[2*DIM+t];
    }
    float gs = block_sum(gv, sred, t);
    float gate = 1.f/(1.f + expf(-gs));
    if(t<DIM) nd[t] = o128[t]*gate + nd[t]*(1.f-gate);
    __syncthreads();
  }

  // ---- LN2 + FFN(gelu exact) + gate2 ----
  dev_ln(nd, xs, ln2_g, ln2_b, sred, t);
  {
    const int cg4 = (t&127)*4, rq = t>>7;
    float4 acc = make_float4(0.f,0.f,0.f,0.f);
#pragma unroll
    for(int f=rq*32; f<rq*32+32; f++){
      float x = xs[f];
      float4 w = *(const float4*)(W1 + f*INNER + cg4);
      acc.x=fmaf(x,w.x,acc.x); acc.y=fmaf(x,w.y,acc.y);
      acc.z=fmaf(x,w.z,acc.z); acc.w=fmaf(x,w.w,acc.w);
    }
    *(float4*)(redS + rq*INNER + cg4) = acc;
  }
  __syncthreads();
  {
    float a = b1[t] + redS[t] + redS[INNER+t] + redS[2*INNER+t] + redS[3*INNER+t];
    qs[t] = 0.5f*a*(1.f + erff(a*0.70710678118654752440f));
  }
  __syncthreads();
  {
    const int cg4 = (t&31)*4, rg = t>>5;
    float4 acc = make_float4(0.f,0.f,0.f,0.f);
#pragma unroll
    for(int m=rg*32; m<rg*32+32; m++){
      float a = qs[m];
      float4 w = *(const float4*)(W2 + m*DIM + cg4);
      acc.x=fmaf(a,w.x,acc.x); acc.y=fmaf(a,w.y,acc.y);
      acc.z=fmaf(a,w.z,acc.z); acc.w=fmaf(a,w.w,acc.w);
    }
    *(float4*)(redS + rg*DIM + cg4) = acc;
    __syncthreads();
    if(t<DIM){
      float s = b2[t];
#pragma unroll
      for(int g=0; g<16; g++) s += redS[g*DIM+t];
      o128[t] = s;
    }
    __syncthreads();
    float gv = 0.f;
    if(t<DIM){
      float y = o128[t], r = nd[t];
      gv = y*Wg2[t] + r*Wg2[DIM+t] + (y-r)*Wg2[2*DIM+t];
    }
    float gs = block_sum(gv, sred, t);
    float gate = 1.f/(1.f + expf(-gs));
    if(t<DIM) nd[t] = o128[t]*gate + nd[t]*(1.f-gate);
    __syncthreads();
  }
  if(t<DIM) nodes[i*DIM+t] = nd[t];

  // ---- next layer's LN1+QKV (writes the OTHER q/k/v buffer: no race) ----
  if(has_next){
    dev_ln(nd, xs, ln1_g_n, ln1_b_n, sred, t);
    dev_qkv4(xs, i, Wq_n, bq_n, Wkv_n, bkv_n, be_n, qg_n, kT_n, vg_n, redS, t);
  }
}

__global__ __launch_bounds__(64) void k_energy(const float* nodes, const float* out_w,
                                               const float* out_b, float* out){
  int i = blockIdx.x, l = threadIdx.x;
  float a = fmaf(nodes[i*DIM+l], out_w[l], nodes[i*DIM+64+l]*out_w[64+l]);
  a = wred_sum(a);
  if(l==0) out[i] = a + out_b[0];
}

extern "C" void kernel_launch(void* const* d_in, const int* in_sizes, int n_in,
                              void* d_out, int out_size, void* d_ws, size_t ws_size,
                              hipStream_t stream){
  const float* coords   = (const float*)d_in[0];
  const int*   bonds    = (const int*  )d_in[1];
  const float* noise    = (const float*)d_in[2];
  const float* atom_emb = (const float*)d_in[3];
  const float* ln1_g = (const float*)d_in[4];
  const float* ln1_b = (const float*)d_in[5];
  const float* Wq    = (const float*)d_in[6];
  const float* bq    = (const float*)d_in[7];
  const float* Wkv   = (const float*)d_in[8];
  const float* bkv   = (const float*)d_in[9];
  const float* We    = (const float*)d_in[10];
  const float* be    = (const float*)d_in[11];
  const float* Wo    = (const float*)d_in[12];
  const float* bo    = (const float*)d_in[13];
  const float* Wg1   = (const float*)d_in[14];
  const float* ln2_g = (const float*)d_in[15];
  const float* ln2_b = (const float*)d_in[16];
  const float* W1    = (const float*)d_in[17];
  const float* b1    = (const float*)d_in[18];
  const float* W2    = (const float*)d_in[19];
  const float* b2    = (const float*)d_in[20];
  const float* Wg2   = (const float*)d_in[21];
  const float* out_w = (const float*)d_in[22];
  const float* out_b = (const float*)d_in[23];

  // workspace (fp32): ~3.3 MB total
  float* ws = (float*)d_ws;
  float* nodes   = ws;                              // 32768 floats
  float* qbuf[2] = { ws +  32768, ws + 163840 };    // 131072 each
  float* kbuf[2] = { ws + 294912, ws + 425984 };    // transposed [o][j]
  float* vbuf[2] = { ws + 557056, ws + 688128 };    // row-major [j][o]

  k_qkv0<<<256, 512, 0, stream>>>(atom_emb, noise, nodes, ln1_g, ln1_b,
                                  Wq, bq, Wkv, bkv, be,
                                  qbuf[0], kbuf[0], vbuf[0]);
  for(int l=0; l<DEPTH; l++){
    int cur = l&1, nxt = cur^1;
    int has_next = (l < DEPTH-1);
    int ln = has_next ? l+1 : l;    // keep pointers valid when unused
    k_layer<<<256, 512, 0, stream>>>(
      nodes, qbuf[cur], kbuf[cur], vbuf[cur],
      qbuf[nxt], kbuf[nxt], vbuf[nxt],
      bonds, coords,
      We  + (size_t)l*3*INNER,
      Wo  + (size_t)l*INNER*DIM, bo + (size_t)l*DIM, Wg1 + (size_t)l*3*DIM,
      ln2_g + (size_t)l*DIM, ln2_b + (size_t)l*DIM,
      W1  + (size_t)l*DIM*4*DIM, b1 + (size_t)l*4*DIM,
      W2  + (size_t)l*4*DIM*DIM, b2 + (size_t)l*DIM, Wg2 + (size_t)l*3*DIM,
      ln1_g + (size_t)ln*DIM, ln1_b + (size_t)ln*DIM,
      Wq  + (size_t)ln*DIM*INNER, bq + (size_t)ln*INNER,
      Wkv + (size_t)ln*DIM*2*INNER, bkv + (size_t)ln*2*INNER,
      be  + (size_t)ln*INNER, has_next);
  }
  k_energy<<<256, 64, 0, stream>>>(nodes, out_w, out_b, (float*)d_out);
}